// Round 1
// baseline (772.784 us; speedup 1.0000x reference)
//
#include <hip/hip_runtime.h>
#include <math.h>

// Problem constants (MahaClassifier): x[B,D], weight[C,D], weight2[D,D]
#define BN 4096
#define CN 32768
#define DN 2048
constexpr float EPS = 1e-12f;

// ---------------------------------------------------------------- k0: zero
__global__ void k0_zero(float* __restrict__ p, int n) {
    int i = blockIdx.x * blockDim.x + threadIdx.x;
    if (i < n) p[i] = 0.0f;
}

// ------------------------------------------- k1: colnorm2[k] = sum_r w2[r,k]^2
// grid: (DN/1024, DN/16) = (2,128), block 256. Each thread owns 4 consecutive
// columns (float4) for a 16-row chunk, then one atomicAdd per column.
__global__ void k1_colnorm(const float* __restrict__ w2, float* __restrict__ colnorm2) {
    int col = blockIdx.x * 1024 + threadIdx.x * 4;
    int r0  = blockIdx.y * 16;
    float4 acc = make_float4(0.f, 0.f, 0.f, 0.f);
    #pragma unroll
    for (int r = 0; r < 16; ++r) {
        const float4 w = *reinterpret_cast<const float4*>(w2 + (size_t)(r0 + r) * DN + col);
        acc.x += w.x * w.x; acc.y += w.y * w.y;
        acc.z += w.z * w.z; acc.w += w.w * w.w;
    }
    atomicAdd(&colnorm2[col + 0], acc.x);
    atomicAdd(&colnorm2[col + 1], acc.y);
    atomicAdd(&colnorm2[col + 2], acc.z);
    atomicAdd(&colnorm2[col + 3], acc.w);
}

// --------------------------------- k2: s[j] = sum_k w2[j,k] / max(colnorm[k],eps)
// One wave (64 lanes) per row, 4 rows/block. inv[] staged in LDS.
__global__ void k2_rowsum(const float* __restrict__ w2, const float* __restrict__ colnorm2,
                          float* __restrict__ s) {
    __shared__ float inv[DN];
    for (int i = threadIdx.x; i < DN; i += 256)
        inv[i] = 1.0f / fmaxf(sqrtf(colnorm2[i]), EPS);
    __syncthreads();

    int wave = threadIdx.x >> 6;
    int lane = threadIdx.x & 63;
    int j = blockIdx.x * 4 + wave;
    const float* row = w2 + (size_t)j * DN;
    float acc = 0.0f;
    #pragma unroll
    for (int it = 0; it < DN / 256; ++it) {
        int k = it * 256 + lane * 4;
        float4 w = *reinterpret_cast<const float4*>(row + k);
        acc += w.x * inv[k] + w.y * inv[k + 1] + w.z * inv[k + 2] + w.w * inv[k + 3];
    }
    #pragma unroll
    for (int off = 32; off > 0; off >>= 1) acc += __shfl_down(acc, off, 64);
    if (lane == 0) s[j] = acc;
}

// ---------------- k3: xs[i] = (x_i . s)/||x_i||  and  ms[c] = (w_c . s)/||w_c||
// One wave per row over the concatenated (B + C) row space.
__global__ void k3_dots(const float* __restrict__ x, const float* __restrict__ w,
                        const float* __restrict__ s,
                        float* __restrict__ xs, float* __restrict__ ms) {
    __shared__ float sh[DN];
    for (int i = threadIdx.x; i < DN; i += 256) sh[i] = s[i];
    __syncthreads();

    int wave = threadIdx.x >> 6;
    int lane = threadIdx.x & 63;
    int r = blockIdx.x * 4 + wave;

    const float* row;
    float* out;
    int o;
    if (r < BN) { row = x + (size_t)r * DN; out = xs; o = r; }
    else        { row = w + (size_t)(r - BN) * DN; out = ms; o = r - BN; }

    float acc = 0.0f, n2 = 0.0f;
    #pragma unroll
    for (int it = 0; it < DN / 256; ++it) {
        int k = it * 256 + lane * 4;
        float4 v = *reinterpret_cast<const float4*>(row + k);
        acc += v.x * sh[k] + v.y * sh[k + 1] + v.z * sh[k + 2] + v.w * sh[k + 3];
        n2  += v.x * v.x + v.y * v.y + v.z * v.z + v.w * v.w;
    }
    #pragma unroll
    for (int off = 32; off > 0; off >>= 1) {
        acc += __shfl_down(acc, off, 64);
        n2  += __shfl_down(n2, off, 64);
    }
    if (lane == 0) out[o] = acc / fmaxf(sqrtf(n2), EPS);
}

// --------------------------------------------- k4: out[i,c] = ms[c] - xs[i]
// grid: (CN/1024, BN), block 256, one float4 store per thread.
__global__ void k4_write(const float* __restrict__ xs, const float* __restrict__ ms,
                         float* __restrict__ out) {
    int c = blockIdx.x * 1024 + threadIdx.x * 4;
    int i = blockIdx.y;
    float xv = xs[i];                  // block-uniform -> scalar load
    float4 m = *reinterpret_cast<const float4*>(ms + c);
    float4 v = make_float4(m.x - xv, m.y - xv, m.z - xv, m.w - xv);
    *reinterpret_cast<float4*>(out + (size_t)i * CN + c) = v;
}

extern "C" void kernel_launch(void* const* d_in, const int* in_sizes, int n_in,
                              void* d_out, int out_size, void* d_ws, size_t ws_size,
                              hipStream_t stream) {
    const float* x  = (const float*)d_in[0];   // [B, D]
    const float* w  = (const float*)d_in[1];   // [C, D]
    const float* w2 = (const float*)d_in[2];   // [D, D]
    float* out = (float*)d_out;                // [B, C]

    // Workspace layout (floats): colnorm2[D] | s[D] | xs[B] | ms[C]
    float* colnorm2 = (float*)d_ws;
    float* s  = colnorm2 + DN;
    float* xs = s + DN;
    float* ms = xs + BN;

    k0_zero<<<(DN + 255) / 256, 256, 0, stream>>>(colnorm2, DN);
    k1_colnorm<<<dim3(DN / 1024, DN / 16), 256, 0, stream>>>(w2, colnorm2);
    k2_rowsum<<<DN / 4, 256, 0, stream>>>(w2, colnorm2, s);
    k3_dots<<<(BN + CN) / 4, 256, 0, stream>>>(x, w, s, xs, ms);
    k4_write<<<dim3(CN / 1024, BN), 256, 0, stream>>>(xs, ms, out);
}